// Round 11
// baseline (178.421 us; speedup 1.0000x reference)
//
#include <hip/hip_runtime.h>
#include <hip/hip_bf16.h>
#include <math.h>

#define BS 128
#define NN 320
#define H1 8
#define F1 18
#define H2C 4
#define F2 46
#define FC0 104
#define FC1 45
#define FC2 84
#define LRA 0.2f
#define DEGCAP 96
#define PW 104   // P row stride in bf16 (208 B: 16B-aligned, 52 dw)

typedef __attribute__((ext_vector_type(8))) short bf16x8;
typedef __attribute__((ext_vector_type(4))) float f32x4;

__device__ __forceinline__ float wave_max64(float v) {
    #pragma unroll
    for (int off = 32; off > 0; off >>= 1)
        v = fmaxf(v, __shfl_xor(v, off, 64));
    return v;
}
__device__ __forceinline__ short bfb(float x) {
    __hip_bfloat16 b = __float2bfloat16(x);
    return *(short*)&b;
}

// ---- K0: CSR build (fwd u16 + transposed u16 + seg meta) + consts + Bb -----
__global__ void k_csr(const float* __restrict__ adj,
                      unsigned short* __restrict__ cols16,
                      unsigned short* __restrict__ colsT16,
                      int4* __restrict__ meta, const float* __restrict__ W1,
                      const float* __restrict__ a1, float* __restrict__ c1s,
                      float* __restrict__ c1d, const float* __restrict__ W2,
                      __hip_bfloat16* __restrict__ Bb) {
    int row = blockIdx.x;
    int lane = threadIdx.x;  // 64 threads
    if (row < NN) {
        int base = 0, c96 = 0, c192 = 0, c288 = 0;
        for (int c0 = 0; c0 < NN; c0 += 64) {
            int j = c0 + lane;
            bool p = (j < NN) && (adj[row * NN + j] > 0.f);
            unsigned long long m = __ballot(p);
            if (p) {
                int pos = base + __popcll(m & ((1ull << lane) - 1ull));
                if (pos < DEGCAP) {
                    cols16[row * DEGCAP + pos] = (unsigned short)j;
                    colsT16[pos * NN + row] = (unsigned short)j;
                }
            }
            base += __popcll(m);
            c96  += __popcll(__ballot(p && j < 96));
            c192 += __popcll(__ballot(p && j < 192));
            c288 += __popcll(__ballot(p && j < 288));
        }
        if (base > DEGCAP) base = DEGCAP;
        if (c96 > DEGCAP) c96 = DEGCAP;
        if (c192 > DEGCAP) c192 = DEGCAP;
        if (c288 > DEGCAP) c288 = DEGCAP;
        for (int q = base + lane; q < DEGCAP; q += 64) {
            cols16[row * DEGCAP + q] = 0;
            colsT16[q * NN + row] = 0;
        }
        if (lane == 0) meta[row] = make_int4(c96, c192, c288, base);
    } else if (row == NN) {
        int h = lane;
        if (h < H1) {
            float s = 0.f, d = 0.f;
            for (int f = 0; f < F1; ++f) {
                float w = W1[h * F1 + f];
                s += w * a1[h * 2 * F1 + f];
                d += w * a1[h * 2 * F1 + F1 + f];
            }
            c1s[h] = s;
            c1d[h] = d;
        }
    } else {
        // Bb[k8][n][e]: n = h*48+f; zero pad cols f>=46 and k>=144
        int idx = (row - NN - 1) * 64 + lane;   // 0..30719
        int e = idx & 7;
        int t = idx >> 3;
        int n = t % 192, k8 = t / 192;
        int k = k8 * 8 + e, hh = n / 48, f = n - hh * 48;
        float v = (k < 144 && f < 46) ? W2[(hh * 144 + k) * 46 + f] : 0.f;
        Bb[idx] = __float2bfloat16(v);
    }
}

// ---- K1: layer-1 GAT, lanes=rows -> out1b bf16 + pool1 partials ------------
// XCD swizzle: block bx -> XCD bx&7 (round-robin heuristic); we place all 8
// writers of out1b[b] on XCD b&7 so out1b[b] stays in one XCD's L2.
__global__ __launch_bounds__(320) void k_l1(
    const float* __restrict__ xn, const unsigned short* __restrict__ colsT16,
    const int4* __restrict__ meta, const float* __restrict__ W1,
    const float* __restrict__ c1s, const float* __restrict__ c1d,
    const float* __restrict__ p1w, __hip_bfloat16* __restrict__ out1b,
    float* __restrict__ part1) {
    int bx = blockIdx.x;
    int k = bx & 7, slot = bx >> 3;          // slot in [0,128)
    int b = k + 8 * (slot >> 3);             // b&7 == k
    int h = slot & 7;
    __shared__ float xb[NN];
    __shared__ float w1h[F1], pwl[F1];
    __shared__ float redmax[5], redmin[5];
    int tid = threadIdx.x;          // == row
    int wv = tid >> 6, lane = tid & 63;
    float xi = xn[b * NN + tid];
    xb[tid] = xi;
    if (tid < F1) { w1h[tid] = W1[h * F1 + tid]; pwl[tid] = p1w[h * F1 + tid]; }
    int Li = meta[tid].w;
    float mx = wave_max64(xi);
    float mn = -wave_max64(-xi);
    int Lmax = (int)wave_max64((float)Li);
    if (lane == 0) { redmax[wv] = mx; redmin[wv] = mn; }
    __syncthreads();
    float MX = redmax[0], MN = redmin[0];
    #pragma unroll
    for (int q = 1; q < 5; ++q) {
        MX = fmaxf(MX, redmax[q]);
        MN = fminf(MN, redmin[q]);
    }
    float cs = c1s[h], cd = c1d[h];
    float u = xi * cs;
    float mt = u + (cd > 0.f ? cd * MX : cd * MN);
    float m = fmaxf(mt, LRA * mt);
    float num = 0.f, den = 0.f;
    const unsigned short* ct = colsT16 + tid;
    int colv = ct[0];
    for (int j = 0; j < Lmax; ++j) {
        int coln = (j + 1 < Lmax) ? ct[(j + 1) * NN] : 0;
        float xj = xb[colv];
        bool act = j < Li;
        float t = fmaf(xj, cd, u);
        t = fmaxf(t, LRA * t);
        float w = __expf(t - m);
        w = act ? w : 0.f;
        num = fmaf(w, xj, num);
        den += w;
        colv = coln;
    }
    float s = num / den;
    // fused: elu(s*w1) -> out1b columns h*18..h*18+17, + pool partial
    float part = 0.f;
    unsigned od[9];
    #pragma unroll
    for (int f = 0; f < F1; f += 2) {
        float v0 = s * w1h[f];
        v0 = v0 > 0.f ? v0 : __expf(v0) - 1.f;
        float v1 = s * w1h[f + 1];
        v1 = v1 > 0.f ? v1 : __expf(v1) - 1.f;
        part = fmaf(v0, pwl[f], part);
        part = fmaf(v1, pwl[f + 1], part);
        od[f >> 1] = (unsigned)(unsigned short)bfb(v0) |
                     ((unsigned)(unsigned short)bfb(v1) << 16);
    }
    __hip_bfloat16* rowp = out1b + (size_t)(b * NN + tid) * 160;
    unsigned* dst = (unsigned*)(rowp + h * F1);
    #pragma unroll
    for (int q = 0; q < 9; ++q) dst[q] = od[q];
    if (h == 0) {
        uint4 z = (uint4){0u, 0u, 0u, 0u};
        *(uint4*)(rowp + 144) = z;
        *(uint4*)(rowp + 152) = z;
    }
    part1[(size_t)(b * 8 + h) * NN + tid] = part;
}

// ---- K2: fused layer-2, row-split + XCD-local ------------------------------
// grid 1024: bx -> (b,h,rh) with b&7 == bx&7 (same XCD as k_l1's writers of
// out1b[b]). Phase 1 (full HT) per block; phase 2 tiles {0,1} / {2,3,4}.
__global__ __launch_bounds__(256) void k_l2(
    const __hip_bfloat16* __restrict__ out1b,
    const unsigned short* __restrict__ cols16,
    const int4* __restrict__ meta, const __hip_bfloat16* __restrict__ Bb,
    const float* __restrict__ a2, const float* __restrict__ p2w,
    float* __restrict__ part2) {
    int bx = blockIdx.x;
    int k = bx & 7, slot = bx >> 3;          // slot in [0,128)
    int b = k + 8 * (slot >> 3);             // b&7 == k
    int h = (slot >> 1) & 3;
    int rh = slot & 1;
    int bh = b * 4 + h;
    __shared__ __align__(16) __hip_bfloat16 HT[48][328];          // 31488 B
    __shared__ __align__(16) __hip_bfloat16 AsP[4][16][PW];       // 13312 B
    __shared__ float esl[NN], edl[NN];                            // 2560 B
    __shared__ float denW[4][16];                                 // 256 B
    __shared__ float pwl[48], a2e[48], a2d[48];                   // 576 B
    __shared__ float Mred[4];                                     // 16 B
    int tid = threadIdx.x, wv = tid >> 6, lane = tid & 63;
    int lr = lane & 15, lq = lane >> 4;
    if (tid < 48) {
        pwl[tid] = tid < 46 ? p2w[h * F2 + tid] : 0.f;
        a2e[tid] = tid < 46 ? a2[h * 92 + tid] : 0.f;
        a2d[tid] = tid < 46 ? a2[h * 92 + 46 + tid] : 0.f;
    }
    // B-fragments in registers (tile-invariant)
    bf16x8 bq[5][3];
    #pragma unroll
    for (int kc = 0; kc < 5; ++kc)
        #pragma unroll
        for (int t = 0; t < 3; ++t)
            bq[kc][t] = *(const bf16x8*)(Bb +
                (size_t)(((kc * 4 + lq) * 192) + h * 48 + t * 16 + lr) * 8);
    __syncthreads();
    // ---------------- phase 1: H = A @ B, HT/es/ed to LDS ----------------
    const __hip_bfloat16* Ag = out1b + (size_t)b * NN * 160;
    for (int tile = 0; tile < 5; ++tile) {
        int r0 = tile * 64;
        const __hip_bfloat16* arow = Ag + (size_t)(r0 + wv * 16 + lr) * 160 + lq * 8;
        f32x4 acc[3];
        #pragma unroll
        for (int t = 0; t < 3; ++t) acc[t] = (f32x4){0.f, 0.f, 0.f, 0.f};
        #pragma unroll
        for (int kc = 0; kc < 5; ++kc) {
            bf16x8 a = *(const bf16x8*)(arow + kc * 32);
            #pragma unroll
            for (int t = 0; t < 3; ++t)
                acc[t] = __builtin_amdgcn_mfma_f32_16x16x32_bf16(
                    a, bq[kc][t], acc[t], 0, 0, 0);
        }
        int node = r0 + wv * 16 + lq * 4;
        #pragma unroll
        for (int t = 0; t < 3; ++t) {
            short4 s4;
            s4.x = bfb(acc[t][0]); s4.y = bfb(acc[t][1]);
            s4.z = bfb(acc[t][2]); s4.w = bfb(acc[t][3]);
            *(short4*)&HT[t * 16 + lr][node] = s4;
        }
        float esa[4] = {0.f, 0.f, 0.f, 0.f}, eda[4] = {0.f, 0.f, 0.f, 0.f};
        #pragma unroll
        for (int t = 0; t < 3; ++t) {
            float ae = a2e[t * 16 + lr], ad = a2d[t * 16 + lr];
            #pragma unroll
            for (int j = 0; j < 4; ++j) {
                esa[j] = fmaf(acc[t][j], ae, esa[j]);
                eda[j] = fmaf(acc[t][j], ad, eda[j]);
            }
        }
        #pragma unroll
        for (int j = 0; j < 4; ++j) {
            #pragma unroll
            for (int off = 1; off < 16; off <<= 1) {
                esa[j] += __shfl_xor(esa[j], off, 64);
                eda[j] += __shfl_xor(eda[j], off, 64);
            }
        }
        if (lr == 0) {
            #pragma unroll
            for (int j = 0; j < 4; ++j) {
                esl[node + j] = esa[j];
                edl[node + j] = eda[j];
            }
        }
    }
    __syncthreads();   // HT/esl/edl complete
    float edmax = -1e30f;
    for (int i = tid; i < NN; i += 256) edmax = fmaxf(edmax, edl[i]);
    float wm = wave_max64(edmax);
    if (lane == 0) Mred[wv] = wm;
    __syncthreads();
    float M = fmaxf(fmaxf(Mred[0], Mred[1]), fmaxf(Mred[2], Mred[3]));
    // ---------------- phase 2: P-fill + P@H + pool ----------------
    int t0i = rh ? 2 : 0;
    int t1i = rh ? 5 : 2;
    for (int tile = t0i; tile < t1i; ++tile) {
        int r0 = tile * 64;
        int i = r0 + wv * 16 + lr;
        int4 mt = meta[i];
        int sb0 = mt.x, sb1 = mt.y, sb2 = mt.z, sb3 = mt.w;
        float es = esl[i];
        float t0 = es + M;
        float m = fmaxf(t0, LRA * t0);
        const unsigned short* crow = cols16 + (size_t)i * DEGCAP;
        f32x4 acc[3];
        #pragma unroll
        for (int t = 0; t < 3; ++t) acc[t] = (f32x4){0.f, 0.f, 0.f, 0.f};
        float dp = 0.f;
        #pragma unroll
        for (int pass = 0; pass < 4; ++pass) {
            // zero only the 96 columns the MFMA reads (3 uint4 per lane)
            for (int q = lane; q < 192; q += 64) {
                int rr = q / 12, cc = q - rr * 12;
                *(uint4*)&AsP[wv][rr][cc * 8] = (uint4){0u, 0u, 0u, 0u};
            }
            int s0 = pass == 0 ? 0 : (pass == 1 ? sb0 : (pass == 2 ? sb1 : sb2));
            int s1 = pass == 0 ? sb0 : (pass == 1 ? sb1 : (pass == 2 ? sb2 : sb3));
            int pofs = pass * 96;
            int j = s0 + lq;
            int col = (j < s1) ? crow[j] : 0;
            for (; j < s1; j += 4) {
                int coln = (j + 4 < s1) ? crow[j + 4] : 0;
                float t = es + edl[col];
                t = fmaxf(t, LRA * t);
                float w = __expf(t - m);
                dp += w;
                AsP[wv][lr][col - pofs] = __float2bfloat16(w);
                col = coln;
            }
            const int nkf = (pass < 3) ? 3 : 1;
            #pragma unroll
            for (int kf = 0; kf < nkf; ++kf) {
                bf16x8 a = *(const bf16x8*)&AsP[wv][lr][kf * 32 + lq * 8];
                #pragma unroll
                for (int t = 0; t < 3; ++t) {
                    bf16x8 bb = *(const bf16x8*)&HT[t * 16 + lr][pofs + kf * 32 + lq * 8];
                    acc[t] = __builtin_amdgcn_mfma_f32_16x16x32_bf16(
                        a, bb, acc[t], 0, 0, 0);
                }
            }
        }
        dp += __shfl_xor(dp, 16, 64);
        dp += __shfl_xor(dp, 32, 64);
        if (lq == 0) denW[wv][lr] = dp;
        float inv[4], part[4];
        #pragma unroll
        for (int j = 0; j < 4; ++j) {
            inv[j] = 1.f / denW[wv][lq * 4 + j];
            part[j] = 0.f;
        }
        #pragma unroll
        for (int t = 0; t < 3; ++t) {
            float pw = pwl[t * 16 + lr];
            #pragma unroll
            for (int j = 0; j < 4; ++j) {
                float v = acc[t][j] * inv[j];
                v = v > 0.f ? v : __expf(v) - 1.f;
                part[j] = fmaf(v, pw, part[j]);
            }
        }
        #pragma unroll
        for (int j = 0; j < 4; ++j) {
            #pragma unroll
            for (int off = 1; off < 16; off <<= 1)
                part[j] += __shfl_xor(part[j], off, 64);
        }
        if (lr == 0) {
            #pragma unroll
            for (int j = 0; j < 4; ++j)
                part2[(size_t)bh * NN + r0 + wv * 16 + lq * 4 + j] = part[j];
        }
    }
}

// ---- K3: x_concat assembly + FC head ---------------------------------------
__global__ __launch_bounds__(256) void k_head(
    const float* __restrict__ xn, const float* __restrict__ part1,
    const float* __restrict__ part2, const float* __restrict__ p1b,
    const float* __restrict__ p2b, const float* __restrict__ e1w,
    const float* __restrict__ e1b, const float* __restrict__ e2w,
    const float* __restrict__ e2b, const float* __restrict__ e3w,
    const float* __restrict__ e3b, const float* __restrict__ cw,
    const float* __restrict__ cb, float* __restrict__ dout) {
    int b = blockIdx.x;
    int tid = threadIdx.x;
    __shared__ float xc[960];
    __shared__ float e1part[2][FC0];
    __shared__ float h1[FC0];
    __shared__ float hh[FC1];
    __shared__ float ft[FC2];
    for (int t = tid; t < NN; t += 256) {
        float x0 = xn[b * NN + t];
        xc[t] = x0;
        dout[b * 960 + t] = x0;
        float s1 = p1b[0];
        #pragma unroll
        for (int h = 0; h < 8; ++h) s1 += part1[(size_t)(b * 8 + h) * NN + t];
        xc[320 + t] = s1;
        dout[b * 960 + 320 + t] = s1;
        float s2 = p2b[0];
        #pragma unroll
        for (int h = 0; h < 4; ++h) s2 += part2[(size_t)(b * 4 + h) * NN + t];
        xc[640 + t] = s2;
        dout[b * 960 + 640 + t] = s2;
    }
    __syncthreads();
    {
        int half = tid >> 7, o = tid & 127;
        if (o < FC0) {
            float a = 0.f;
            int k0 = half * 480;
            for (int k = k0; k < k0 + 480; ++k)
                a = fmaf(xc[k], e1w[k * FC0 + o], a);
            e1part[half][o] = a;
        }
    }
    __syncthreads();
    if (tid < FC0) {
        float a = e1b[tid] + e1part[0][tid] + e1part[1][tid];
        h1[tid] = a > 0.f ? a : expm1f(a);
    }
    __syncthreads();
    if (tid < FC1) {
        float a = e2b[tid];
        for (int k = 0; k < FC0; ++k) a += h1[k] * e2w[k * FC1 + tid];
        hh[tid] = a > 0.f ? a : expm1f(a);
    }
    __syncthreads();
    if (tid < FC2) {
        float a = e3b[tid];
        for (int k = 0; k < FC1; ++k) a += hh[k] * e3w[k * FC2 + tid];
        a = a > 0.f ? a : expm1f(a);
        ft[tid] = a;
        dout[BS * 960 + b * FC2 + tid] = a;
    }
    __syncthreads();
    if (tid < 64) {
        float v = 0.f;
        for (int t = tid; t < FC2; t += 64) v += ft[t] * cw[t];
        #pragma unroll
        for (int off = 32; off > 0; off >>= 1) v += __shfl_xor(v, off, 64);
        if (tid == 0) dout[BS * 960 + BS * FC2 + b] = v + cb[0];
    }
}

extern "C" void kernel_launch(void* const* d_in, const int* in_sizes, int n_in,
                              void* d_out, int out_size, void* d_ws,
                              size_t ws_size, hipStream_t stream) {
    const float* xn  = (const float*)d_in[0];
    const float* adj = (const float*)d_in[1];
    const float* W1  = (const float*)d_in[2];
    const float* a1  = (const float*)d_in[3];
    const float* W2  = (const float*)d_in[4];
    const float* a2  = (const float*)d_in[5];
    const float* p1w = (const float*)d_in[6];
    const float* p1b = (const float*)d_in[7];
    const float* p2w = (const float*)d_in[8];
    const float* p2b = (const float*)d_in[9];
    const float* e1w = (const float*)d_in[10];
    const float* e1b = (const float*)d_in[11];
    const float* e2w = (const float*)d_in[12];
    const float* e2b = (const float*)d_in[13];
    const float* e3w = (const float*)d_in[14];
    const float* e3b = (const float*)d_in[15];
    const float* cw  = (const float*)d_in[16];
    const float* cb  = (const float*)d_in[17];

    char* ws = (char*)d_ws;
    int4*  meta     = (int4*)ws;                               // 5120
    float* c1s      = (float*)(ws + 5120);                     // 32
    float* c1d      = (float*)(ws + 5152);                     // 32 (pad->5248)
    unsigned short* cols16  = (unsigned short*)(ws + 5248);    // 61440 -> 66688
    unsigned short* colsT16 = (unsigned short*)(ws + 66688);   // 61440 -> 128128
    __hip_bfloat16* Bb = (__hip_bfloat16*)(ws + 128128);       // 61440 -> 189568
    __hip_bfloat16* out1b = (__hip_bfloat16*)(ws + 189568);    // 13107200 -> 13296768
    float* part1    = (float*)(ws + 13296768);                 // 1310720 -> 14607488
    float* part2    = (float*)(ws + 14607488);                 // 655360 -> 15262848
    float* dout     = (float*)d_out;

    k_csr<<<NN + 1 + 480, 64, 0, stream>>>(adj, cols16, colsT16, meta,
                                           W1, a1, c1s, c1d, W2, Bb);
    k_l1<<<BS * H1, 320, 0, stream>>>(xn, colsT16, meta, W1, c1s, c1d,
                                      p1w, out1b, part1);
    k_l2<<<BS * H2C * 2, 256, 0, stream>>>(out1b, cols16, meta, Bb, a2, p2w, part2);
    k_head<<<BS, 256, 0, stream>>>(xn, part1, part2, p1b, p2b, e1w, e1b,
                                   e2w, e2b, e3w, e3b, cw, cb, dout);
}

// Round 13
// 168.457 us; speedup vs baseline: 1.0591x; 1.0591x over previous
//
#include <hip/hip_runtime.h>
#include <hip/hip_bf16.h>
#include <math.h>

#define BS 128
#define NN 320
#define H1 8
#define F1 18
#define H2C 4
#define F2 46
#define FC0 104
#define FC1 45
#define FC2 84
#define LRA 0.2f
#define DEGCAP 96
#define HW 328   // HT row stride in bf16 (656 B, 164 dw = 4 mod 32 banks)
#define APW 200  // AsP row stride in bf16 (400 B, 100 dw = 4 mod 32 banks)

typedef __attribute__((ext_vector_type(8))) short bf16x8;
typedef __attribute__((ext_vector_type(4))) float f32x4;

__device__ __forceinline__ float wave_max64(float v) {
    #pragma unroll
    for (int off = 32; off > 0; off >>= 1)
        v = fmaxf(v, __shfl_xor(v, off, 64));
    return v;
}
__device__ __forceinline__ short bfb(float x) {
    __hip_bfloat16 b = __float2bfloat16(x);
    return *(short*)&b;
}

// ---- K0: CSR build (fwd u16 + transposed u16 + meta) + consts + Bb ---------
__global__ void k_csr(const float* __restrict__ adj,
                      unsigned short* __restrict__ cols16,
                      unsigned short* __restrict__ colsT16,
                      int4* __restrict__ meta, const float* __restrict__ W1,
                      const float* __restrict__ a1, float* __restrict__ c1s,
                      float* __restrict__ c1d, const float* __restrict__ W2,
                      __hip_bfloat16* __restrict__ Bb) {
    int row = blockIdx.x;
    int lane = threadIdx.x;  // 64 threads
    if (row < NN) {
        int base = 0, c96 = 0, c192 = 0, c288 = 0;
        for (int c0 = 0; c0 < NN; c0 += 64) {
            int j = c0 + lane;
            bool p = (j < NN) && (adj[row * NN + j] > 0.f);
            unsigned long long m = __ballot(p);
            if (p) {
                int pos = base + __popcll(m & ((1ull << lane) - 1ull));
                if (pos < DEGCAP) {
                    cols16[row * DEGCAP + pos] = (unsigned short)j;
                    colsT16[pos * NN + row] = (unsigned short)j;
                }
            }
            base += __popcll(m);
            c96  += __popcll(__ballot(p && j < 96));
            c192 += __popcll(__ballot(p && j < 192));
            c288 += __popcll(__ballot(p && j < 288));
        }
        if (base > DEGCAP) base = DEGCAP;
        if (c96 > DEGCAP) c96 = DEGCAP;
        if (c192 > DEGCAP) c192 = DEGCAP;
        if (c288 > DEGCAP) c288 = DEGCAP;
        for (int q = base + lane; q < DEGCAP; q += 64) {
            cols16[row * DEGCAP + q] = 0;
            colsT16[q * NN + row] = 0;
        }
        if (lane == 0) meta[row] = make_int4(c96, c192, c288, base);
    } else if (row == NN) {
        int h = lane;
        if (h < H1) {
            float s = 0.f, d = 0.f;
            for (int f = 0; f < F1; ++f) {
                float w = W1[h * F1 + f];
                s += w * a1[h * 2 * F1 + f];
                d += w * a1[h * 2 * F1 + F1 + f];
            }
            c1s[h] = s;
            c1d[h] = d;
        }
    } else {
        // Bb[k8][n][e]: n = h*48+f; zero pad cols f>=46 and k>=144
        int idx = (row - NN - 1) * 64 + lane;   // 0..30719
        int e = idx & 7;
        int t = idx >> 3;
        int n = t % 192, k8 = t / 192;
        int k = k8 * 8 + e, hh = n / 48, f = n - hh * 48;
        float v = (k < 144 && f < 46) ? W2[(hh * 144 + k) * 46 + f] : 0.f;
        Bb[idx] = __float2bfloat16(v);
    }
}

// ---- K1: layer-1 GAT, lanes=rows -> out1b bf16 + pool1 partials ------------
// XCD swizzle: all 8 writers of out1b[b] land on XCD b&7 (round-robin
// heuristic) so out1b[b] stays in one XCD's L2. [R10: FETCH 26->7 MB]
__global__ __launch_bounds__(320) void k_l1(
    const float* __restrict__ xn, const unsigned short* __restrict__ colsT16,
    const int4* __restrict__ meta, const float* __restrict__ W1,
    const float* __restrict__ c1s, const float* __restrict__ c1d,
    const float* __restrict__ p1w, __hip_bfloat16* __restrict__ out1b,
    float* __restrict__ part1) {
    int bx = blockIdx.x;
    int k = bx & 7, slot = bx >> 3;          // slot in [0,128)
    int b = k + 8 * (slot >> 3);             // b&7 == k
    int h = slot & 7;
    __shared__ float xb[NN];
    __shared__ float w1h[F1], pwl[F1];
    __shared__ float redmax[5], redmin[5];
    int tid = threadIdx.x;          // == row
    int wv = tid >> 6, lane = tid & 63;
    float xi = xn[b * NN + tid];
    xb[tid] = xi;
    if (tid < F1) { w1h[tid] = W1[h * F1 + tid]; pwl[tid] = p1w[h * F1 + tid]; }
    int Li = meta[tid].w;
    float mx = wave_max64(xi);
    float mn = -wave_max64(-xi);
    int Lmax = (int)wave_max64((float)Li);
    if (lane == 0) { redmax[wv] = mx; redmin[wv] = mn; }
    __syncthreads();
    float MX = redmax[0], MN = redmin[0];
    #pragma unroll
    for (int q = 1; q < 5; ++q) {
        MX = fmaxf(MX, redmax[q]);
        MN = fminf(MN, redmin[q]);
    }
    float cs = c1s[h], cd = c1d[h];
    float u = xi * cs;
    float mt = u + (cd > 0.f ? cd * MX : cd * MN);
    float m = fmaxf(mt, LRA * mt);
    float num = 0.f, den = 0.f;
    const unsigned short* ct = colsT16 + tid;
    int colv = ct[0];
    for (int j = 0; j < Lmax; ++j) {
        int coln = (j + 1 < Lmax) ? ct[(j + 1) * NN] : 0;
        float xj = xb[colv];
        bool act = j < Li;
        float t = fmaf(xj, cd, u);
        t = fmaxf(t, LRA * t);
        float w = __expf(t - m);
        w = act ? w : 0.f;
        num = fmaf(w, xj, num);
        den += w;
        colv = coln;
    }
    float s = num / den;
    // fused: elu(s*w1) -> out1b columns h*18..h*18+17, + pool partial
    float part = 0.f;
    unsigned od[9];
    #pragma unroll
    for (int f = 0; f < F1; f += 2) {
        float v0 = s * w1h[f];
        v0 = v0 > 0.f ? v0 : __expf(v0) - 1.f;
        float v1 = s * w1h[f + 1];
        v1 = v1 > 0.f ? v1 : __expf(v1) - 1.f;
        part = fmaf(v0, pwl[f], part);
        part = fmaf(v1, pwl[f + 1], part);
        od[f >> 1] = (unsigned)(unsigned short)bfb(v0) |
                     ((unsigned)(unsigned short)bfb(v1) << 16);
    }
    __hip_bfloat16* rowp = out1b + (size_t)(b * NN + tid) * 160;
    unsigned* dst = (unsigned*)(rowp + h * F1);
    #pragma unroll
    for (int q = 0; q < 9; ++q) dst[q] = od[q];
    if (h == 0) {
        uint4 z = (uint4){0u, 0u, 0u, 0u};
        *(uint4*)(rowp + 144) = z;
        *(uint4*)(rowp + 152) = z;
    }
    part1[(size_t)(b * 8 + h) * NN + tid] = part;
}

// ---- K2: fused layer-2, TWO-pass phase 2, XCD-local ------------------------
// grid 512: bx -> (b,h) with b&7 == bx&7 (same XCD as out1b[b]'s writers).
// LDS = 60,496 B. HARD CONSTRAINT learned R11: per-WORKGROUP static LDS
// limit is 64 KiB (65,536) — the 76.9 KB single-pass variant failed its
// launch silently (part2 never written, absmax 0.405 == max|x2|). 160 KB
// is per-CU capacity, not per-block. Phase 2 splits K at col 192 (meta.y):
// pass0 = 6 kf-steps, pass1 = 4 — vs 4 segmented passes before.
// NOTE: plain launch_bounds — (256,3) capped VGPR at 84 and spilled bq[]
// to scratch (R8: WRITE 0.6->10.4 MB, +8 us).
__global__ __launch_bounds__(256) void k_l2(
    const __hip_bfloat16* __restrict__ out1b,
    const unsigned short* __restrict__ cols16,
    const int4* __restrict__ meta, const __hip_bfloat16* __restrict__ Bb,
    const float* __restrict__ a2, const float* __restrict__ p2w,
    float* __restrict__ part2) {
    int bx = blockIdx.x;
    int k = bx & 7, slot = bx >> 3;          // slot in [0,64)
    int b = k + 8 * (slot >> 2);             // b&7 == k
    int h = slot & 3;
    int bh = b * 4 + h;
    __shared__ __align__(16) __hip_bfloat16 HT[48][HW];           // 31488 B
    __shared__ __align__(16) __hip_bfloat16 AsP[4][16][APW];      // 25600 B
    __shared__ float esl[NN], edl[NN];                            // 2560 B
    __shared__ float denW[4][16];                                 // 256 B
    __shared__ float pwl[48], a2e[48], a2d[48];                   // 576 B
    __shared__ float Mred[4];                                     // 16 B
    int tid = threadIdx.x, wv = tid >> 6, lane = tid & 63;
    int lr = lane & 15, lq = lane >> 4;
    if (tid < 48) {
        pwl[tid] = tid < 46 ? p2w[h * F2 + tid] : 0.f;
        a2e[tid] = tid < 46 ? a2[h * 92 + tid] : 0.f;
        a2d[tid] = tid < 46 ? a2[h * 92 + 46 + tid] : 0.f;
    }
    // B-fragments in registers (tile-invariant)
    bf16x8 bq[5][3];
    #pragma unroll
    for (int kc = 0; kc < 5; ++kc)
        #pragma unroll
        for (int t = 0; t < 3; ++t)
            bq[kc][t] = *(const bf16x8*)(Bb +
                (size_t)(((kc * 4 + lq) * 192) + h * 48 + t * 16 + lr) * 8);
    __syncthreads();
    // ---------------- phase 1: H = A @ B, HT/es/ed to LDS ----------------
    const __hip_bfloat16* Ag = out1b + (size_t)b * NN * 160;
    for (int tile = 0; tile < 5; ++tile) {
        int r0 = tile * 64;
        const __hip_bfloat16* arow = Ag + (size_t)(r0 + wv * 16 + lr) * 160 + lq * 8;
        f32x4 acc[3];
        #pragma unroll
        for (int t = 0; t < 3; ++t) acc[t] = (f32x4){0.f, 0.f, 0.f, 0.f};
        #pragma unroll
        for (int kc = 0; kc < 5; ++kc) {
            bf16x8 a = *(const bf16x8*)(arow + kc * 32);
            #pragma unroll
            for (int t = 0; t < 3; ++t)
                acc[t] = __builtin_amdgcn_mfma_f32_16x16x32_bf16(
                    a, bq[kc][t], acc[t], 0, 0, 0);
        }
        int node = r0 + wv * 16 + lq * 4;
        #pragma unroll
        for (int t = 0; t < 3; ++t) {
            short4 s4;
            s4.x = bfb(acc[t][0]); s4.y = bfb(acc[t][1]);
            s4.z = bfb(acc[t][2]); s4.w = bfb(acc[t][3]);
            *(short4*)&HT[t * 16 + lr][node] = s4;
        }
        float esa[4] = {0.f, 0.f, 0.f, 0.f}, eda[4] = {0.f, 0.f, 0.f, 0.f};
        #pragma unroll
        for (int t = 0; t < 3; ++t) {
            float ae = a2e[t * 16 + lr], ad = a2d[t * 16 + lr];
            #pragma unroll
            for (int j = 0; j < 4; ++j) {
                esa[j] = fmaf(acc[t][j], ae, esa[j]);
                eda[j] = fmaf(acc[t][j], ad, eda[j]);
            }
        }
        #pragma unroll
        for (int j = 0; j < 4; ++j) {
            #pragma unroll
            for (int off = 1; off < 16; off <<= 1) {
                esa[j] += __shfl_xor(esa[j], off, 64);
                eda[j] += __shfl_xor(eda[j], off, 64);
            }
        }
        if (lr == 0) {
            #pragma unroll
            for (int j = 0; j < 4; ++j) {
                esl[node + j] = esa[j];
                edl[node + j] = eda[j];
            }
        }
    }
    __syncthreads();   // HT/esl/edl complete
    float edmax = -1e30f;
    for (int i = tid; i < NN; i += 256) edmax = fmaxf(edmax, edl[i]);
    float wm = wave_max64(edmax);
    if (lane == 0) Mred[wv] = wm;
    __syncthreads();
    float M = fmaxf(fmaxf(Mred[0], Mred[1]), fmaxf(Mred[2], Mred[3]));
    // ---------------- phase 2: 2-pass P-fill + P@H + pool ----------------
    for (int tile = 0; tile < 5; ++tile) {
        int r0 = tile * 64;
        int i = r0 + wv * 16 + lr;
        int4 mt = meta[i];
        int c192 = mt.y, deg = mt.w;
        float es = esl[i];
        float t0 = es + M;
        float m = fmaxf(t0, LRA * t0);
        const unsigned short* crow = cols16 + (size_t)i * DEGCAP;
        f32x4 acc[3];
        #pragma unroll
        for (int t = 0; t < 3; ++t) acc[t] = (f32x4){0.f, 0.f, 0.f, 0.f};
        float dp = 0.f;
        #pragma unroll
        for (int pass = 0; pass < 2; ++pass) {
            // zero this wave's 16 P-rows (25 uint4 per row)
            for (int q = lane; q < 400; q += 64) {
                int rr = q / 25, cc = q - rr * 25;
                *(uint4*)&AsP[wv][rr][cc * 8] = (uint4){0u, 0u, 0u, 0u};
            }
            int s0 = pass ? c192 : 0;
            int s1 = pass ? deg : c192;
            int pofs = pass * 192;
            int j = s0 + lq;
            int col = (j < s1) ? crow[j] : 0;
            for (; j < s1; j += 4) {
                int coln = (j + 4 < s1) ? crow[j + 4] : 0;
                float t = es + edl[col];
                t = fmaxf(t, LRA * t);
                float w = __expf(t - m);
                dp += w;
                AsP[wv][lr][col - pofs] = __float2bfloat16(w);
                col = coln;
            }
            // wave-local: wave wv wrote only rows wv*16..+15, the rows it reads
            const int nkf = pass ? 4 : 6;
            #pragma unroll
            for (int kf = 0; kf < 6; ++kf) {
                if (kf >= nkf) break;
                bf16x8 a = *(const bf16x8*)&AsP[wv][lr][kf * 32 + lq * 8];
                #pragma unroll
                for (int t = 0; t < 3; ++t) {
                    bf16x8 bb = *(const bf16x8*)&HT[t * 16 + lr][pofs + kf * 32 + lq * 8];
                    acc[t] = __builtin_amdgcn_mfma_f32_16x16x32_bf16(
                        a, bb, acc[t], 0, 0, 0);
                }
            }
        }
        dp += __shfl_xor(dp, 16, 64);
        dp += __shfl_xor(dp, 32, 64);
        if (lq == 0) denW[wv][lr] = dp;
        float inv[4], part[4];
        #pragma unroll
        for (int j2 = 0; j2 < 4; ++j2) {
            inv[j2] = 1.f / denW[wv][lq * 4 + j2];
            part[j2] = 0.f;
        }
        #pragma unroll
        for (int t = 0; t < 3; ++t) {
            float pw = pwl[t * 16 + lr];
            #pragma unroll
            for (int j2 = 0; j2 < 4; ++j2) {
                float v = acc[t][j2] * inv[j2];
                v = v > 0.f ? v : __expf(v) - 1.f;
                part[j2] = fmaf(v, pw, part[j2]);
            }
        }
        #pragma unroll
        for (int j2 = 0; j2 < 4; ++j2) {
            #pragma unroll
            for (int off = 1; off < 16; off <<= 1)
                part[j2] += __shfl_xor(part[j2], off, 64);
        }
        if (lr == 0) {
            #pragma unroll
            for (int j2 = 0; j2 < 4; ++j2)
                part2[(size_t)bh * NN + r0 + wv * 16 + lq * 4 + j2] = part[j2];
        }
    }
}

// ---- K3: x_concat assembly + FC head ---------------------------------------
__global__ __launch_bounds__(256) void k_head(
    const float* __restrict__ xn, const float* __restrict__ part1,
    const float* __restrict__ part2, const float* __restrict__ p1b,
    const float* __restrict__ p2b, const float* __restrict__ e1w,
    const float* __restrict__ e1b, const float* __restrict__ e2w,
    const float* __restrict__ e2b, const float* __restrict__ e3w,
    const float* __restrict__ e3b, const float* __restrict__ cw,
    const float* __restrict__ cb, float* __restrict__ dout) {
    int b = blockIdx.x;
    int tid = threadIdx.x;
    __shared__ float xc[960];
    __shared__ float e1part[2][FC0];
    __shared__ float h1[FC0];
    __shared__ float hh[FC1];
    __shared__ float ft[FC2];
    for (int t = tid; t < NN; t += 256) {
        float x0 = xn[b * NN + t];
        xc[t] = x0;
        dout[b * 960 + t] = x0;
        float s1 = p1b[0];
        #pragma unroll
        for (int h = 0; h < 8; ++h) s1 += part1[(size_t)(b * 8 + h) * NN + t];
        xc[320 + t] = s1;
        dout[b * 960 + 320 + t] = s1;
        float s2 = p2b[0];
        #pragma unroll
        for (int h = 0; h < 4; ++h) s2 += part2[(size_t)(b * 4 + h) * NN + t];
        xc[640 + t] = s2;
        dout[b * 960 + 640 + t] = s2;
    }
    __syncthreads();
    {
        int half = tid >> 7, o = tid & 127;
        if (o < FC0) {
            float a = 0.f;
            int k0 = half * 480;
            for (int k = k0; k < k0 + 480; ++k)
                a = fmaf(xc[k], e1w[k * FC0 + o], a);
            e1part[half][o] = a;
        }
    }
    __syncthreads();
    if (tid < FC0) {
        float a = e1b[tid] + e1part[0][tid] + e1part[1][tid];
        h1[tid] = a > 0.f ? a : expm1f(a);
    }
    __syncthreads();
    if (tid < FC1) {
        float a = e2b[tid];
        for (int k = 0; k < FC0; ++k) a += h1[k] * e2w[k * FC1 + tid];
        hh[tid] = a > 0.f ? a : expm1f(a);
    }
    __syncthreads();
    if (tid < FC2) {
        float a = e3b[tid];
        for (int k = 0; k < FC1; ++k) a += hh[k] * e3w[k * FC2 + tid];
        a = a > 0.f ? a : expm1f(a);
        ft[tid] = a;
        dout[BS * 960 + b * FC2 + tid] = a;
    }
    __syncthreads();
    if (tid < 64) {
        float v = 0.f;
        for (int t = tid; t < FC2; t += 64) v += ft[t] * cw[t];
        #pragma unroll
        for (int off = 32; off > 0; off >>= 1) v += __shfl_xor(v, off, 64);
        if (tid == 0) dout[BS * 960 + BS * FC2 + b] = v + cb[0];
    }
}

extern "C" void kernel_launch(void* const* d_in, const int* in_sizes, int n_in,
                              void* d_out, int out_size, void* d_ws,
                              size_t ws_size, hipStream_t stream) {
    const float* xn  = (const float*)d_in[0];
    const float* adj = (const float*)d_in[1];
    const float* W1  = (const float*)d_in[2];
    const float* a1  = (const float*)d_in[3];
    const float* W2  = (const float*)d_in[4];
    const float* a2  = (const float*)d_in[5];
    const float* p1w = (const float*)d_in[6];
    const float* p1b = (const float*)d_in[7];
    const float* p2w = (const float*)d_in[8];
    const float* p2b = (const float*)d_in[9];
    const float* e1w = (const float*)d_in[10];
    const float* e1b = (const float*)d_in[11];
    const float* e2w = (const float*)d_in[12];
    const float* e2b = (const float*)d_in[13];
    const float* e3w = (const float*)d_in[14];
    const float* e3b = (const float*)d_in[15];
    const float* cw  = (const float*)d_in[16];
    const float* cb  = (const float*)d_in[17];

    char* ws = (char*)d_ws;
    int4*  meta     = (int4*)ws;                               // 5120
    float* c1s      = (float*)(ws + 5120);                     // 32
    float* c1d      = (float*)(ws + 5152);                     // 32 (pad->5248)
    unsigned short* cols16  = (unsigned short*)(ws + 5248);    // 61440 -> 66688
    unsigned short* colsT16 = (unsigned short*)(ws + 66688);   // 61440 -> 128128
    __hip_bfloat16* Bb = (__hip_bfloat16*)(ws + 128128);       // 61440 -> 189568
    __hip_bfloat16* out1b = (__hip_bfloat16*)(ws + 189568);    // 13107200 -> 13296768
    float* part1    = (float*)(ws + 13296768);                 // 1310720 -> 14607488
    float* part2    = (float*)(ws + 14607488);                 // 655360 -> 15262848
    float* dout     = (float*)d_out;

    k_csr<<<NN + 1 + 480, 64, 0, stream>>>(adj, cols16, colsT16, meta,
                                           W1, a1, c1s, c1d, W2, Bb);
    k_l1<<<BS * H1, 320, 0, stream>>>(xn, colsT16, meta, W1, c1s, c1d,
                                      p1w, out1b, part1);
    k_l2<<<BS * H2C, 256, 0, stream>>>(out1b, cols16, meta, Bb, a2, p2w, part2);
    k_head<<<BS, 256, 0, stream>>>(xn, part1, part2, p1b, p2b, e1w, e1b,
                                   e2w, e2b, e3w, e3b, cw, cb, dout);
}